// Round 14
// baseline (467.534 us; speedup 1.0000x reference)
//
#include <hip/hip_runtime.h>
#include <hip/hip_cooperative_groups.h>
#include <hip/hip_fp16.h>
#include <math.h>

namespace cg = cooperative_groups;

#define FDIM   64
#define NB     128     // nodes per block in pre_gemm part
#define BSHIFT 8       // coarse bucket = 256 nodes
#define BMASK  255
#define EPTA   16      // edges per thread in build
#define CHUNKA (EPTA * 256)   // 4096
#define DMASK  0xFFFFF // dst fits in 20 bits (N = 100000 < 2^20)
#define MAXBKT 512

// ================= cooperative build kernel: zero + count + scan + scatter ==========
// Registers (S/D/A/C) and LDS (lhist) persist across grid.sync() — one edge sweep.
__global__ __launch_bounds__(256) void build_k(const int* __restrict__ src,
                                               const int* __restrict__ dst,
                                               const float* __restrict__ amount,
                                               const float* __restrict__ count,
                                               float* __restrict__ out,
                                               int* __restrict__ bktTotal,
                                               double* __restrict__ colsum,
                                               int* __restrict__ bbase,
                                               int* __restrict__ cursor,
                                               float4* __restrict__ partial,
                                               float* __restrict__ mmf,
                                               int2* __restrict__ payload,
                                               int E, int N, int nbkt, int nblkA) {
  cg::grid_group grid = cg::this_grid();
  __shared__ int lhist[MAXBKT];
  __shared__ int lcur[MAXBKT];
  __shared__ int tmp[256];
  __shared__ float4 lred[4];
  const int t = threadIdx.x;
  const int gtid = blockIdx.x * 256 + t;
  const int nthr = gridDim.x * 256;

  // ---- phase 0: zero out[], bktTotal, colsum ----
  {
    float4* o4 = (float4*)out;
    const int tot4 = N * FDIM / 4;
    const float4 z = make_float4(0.f, 0.f, 0.f, 0.f);
    for (int i = gtid; i < tot4; i += nthr) o4[i] = z;
    if (blockIdx.x == 0) {
      for (int k = t; k < nbkt; k += 256) bktTotal[k] = 0;
      for (int k = t; k < 1024; k += 256) colsum[k] = 0.0;
    }
  }
  for (int k = t; k < nbkt; k += 256) lhist[k] = 0;
  grid.sync();

  // ---- phase 1: count + minmax; retain edge data in registers ----
  float amin = 3.4e38f, amax = -3.4e38f, cmin = 3.4e38f, cmax = -3.4e38f;
  const int e0 = blockIdx.x * CHUNKA + t * EPTA;
  const bool full = (e0 + EPTA <= E);
  int4 S[4]; int4 D[4]; float4 A[4]; float4 C[4];
  if (full) {
    #pragma unroll
    for (int q = 0; q < 4; q++) {
      S[q] = *(const int4*)(src + e0 + 4 * q);
      D[q] = *(const int4*)(dst + e0 + 4 * q);
      A[q] = *(const float4*)(amount + e0 + 4 * q);
      C[q] = *(const float4*)(count + e0 + 4 * q);
      atomicAdd(&lhist[S[q].x >> BSHIFT], 1);
      atomicAdd(&lhist[S[q].y >> BSHIFT], 1);
      atomicAdd(&lhist[S[q].z >> BSHIFT], 1);
      atomicAdd(&lhist[S[q].w >> BSHIFT], 1);
      amin = fminf(amin, fminf(fminf(A[q].x, A[q].y), fminf(A[q].z, A[q].w)));
      amax = fmaxf(amax, fmaxf(fmaxf(A[q].x, A[q].y), fmaxf(A[q].z, A[q].w)));
      cmin = fminf(cmin, fminf(fminf(C[q].x, C[q].y), fminf(C[q].z, C[q].w)));
      cmax = fmaxf(cmax, fmaxf(fmaxf(C[q].x, C[q].y), fmaxf(C[q].z, C[q].w)));
    }
  } else {
    for (int e = e0; e < E; e++) {
      atomicAdd(&lhist[src[e] >> BSHIFT], 1);
      float a = amount[e], c = count[e];
      amin = fminf(amin, a); amax = fmaxf(amax, a);
      cmin = fminf(cmin, c); cmax = fmaxf(cmax, c);
    }
  }
  #pragma unroll
  for (int off = 32; off; off >>= 1) {
    amin = fminf(amin, __shfl_down(amin, off));
    amax = fmaxf(amax, __shfl_down(amax, off));
    cmin = fminf(cmin, __shfl_down(cmin, off));
    cmax = fmaxf(cmax, __shfl_down(cmax, off));
  }
  if ((t & 63) == 0) lred[t >> 6] = make_float4(amin, amax, cmin, cmax);
  __syncthreads();
  for (int k = t; k < nbkt; k += 256)
    if (lhist[k]) atomicAdd(&bktTotal[k], lhist[k]);
  if (t == 0) {
    float4 r = lred[0];
    #pragma unroll
    for (int w = 1; w < 4; w++) {
      r.x = fminf(r.x, lred[w].x); r.y = fmaxf(r.y, lred[w].y);
      r.z = fminf(r.z, lred[w].z); r.w = fmaxf(r.w, lred[w].w);
    }
    partial[blockIdx.x] = r;
  }
  grid.sync();

  // ---- phase 2: block 0 scans bucket totals + reduces minmax ----
  if (blockIdx.x == 0) {
    int running = 0;
    for (int c0 = 0; c0 < nbkt; c0 += 256) {
      int x = (c0 + t < nbkt) ? bktTotal[c0 + t] : 0;
      tmp[t] = x; __syncthreads();
      for (int off = 1; off < 256; off <<= 1) {
        int v = (t >= off) ? tmp[t - off] : 0;
        __syncthreads();
        tmp[t] += v; __syncthreads();
      }
      if (c0 + t < nbkt) {
        int b = running + tmp[t] - x;
        bbase[c0 + t] = b;
        cursor[c0 + t] = b;
      }
      running += tmp[255];
      __syncthreads();
    }
    if (t == 0) bbase[nbkt] = E;
    float am = 3.4e38f, ax = -3.4e38f, cm = 3.4e38f, cx = -3.4e38f;
    for (int i = t; i < nblkA; i += 256) {
      float4 p = partial[i];
      am = fminf(am, p.x); ax = fmaxf(ax, p.y);
      cm = fminf(cm, p.z); cx = fmaxf(cx, p.w);
    }
    #pragma unroll
    for (int off = 32; off; off >>= 1) {
      am = fminf(am, __shfl_down(am, off));
      ax = fmaxf(ax, __shfl_down(ax, off));
      cm = fminf(cm, __shfl_down(cm, off));
      cx = fmaxf(cx, __shfl_down(cx, off));
    }
    __syncthreads();
    if ((t & 63) == 0) lred[t >> 6] = make_float4(am, ax, cm, cx);
    __syncthreads();
    if (t == 0) {
      float4 r = lred[0];
      #pragma unroll
      for (int w = 1; w < 4; w++) {
        r.x = fminf(r.x, lred[w].x); r.y = fmaxf(r.y, lred[w].y);
        r.z = fminf(r.z, lred[w].z); r.w = fmaxf(r.w, lred[w].w);
      }
      mmf[0] = r.x; mmf[1] = r.y; mmf[2] = r.z; mmf[3] = r.w;
    }
  }
  grid.sync();

  // ---- phase 3: reserve chunks, scatter retained registers to payload ----
  const float famin = mmf[0], famax = mmf[1], fcmin = mmf[2], fcmax = mmf[3];
  const float L2E = 1.4426950408889634f;
  const float ascale = 0.5f * L2E / (famax - famin + 1e-8f);
  const float cscale = 0.5f * L2E / (fcmax - fcmin + 1e-8f);
  for (int k = t; k < nbkt; k += 256)
    lcur[k] = lhist[k] ? atomicAdd(&cursor[k], lhist[k]) : 0;
  __syncthreads();
  auto ins = [&](int s, int d, float a, float c) {
    int b = s >> BSHIFT;
    float ew = (a - famin) * ascale + (c - fcmin) * cscale;
    int pos = atomicAdd(&lcur[b], 1);
    payload[pos] = make_int2(d | ((s & BMASK) << 20), __float_as_int(ew));
  };
  if (full) {
    #pragma unroll
    for (int q = 0; q < 4; q++) {
      ins(S[q].x, D[q].x, A[q].x, C[q].x);
      ins(S[q].y, D[q].y, A[q].y, C[q].y);
      ins(S[q].z, D[q].z, A[q].z, C[q].z);
      ins(S[q].w, D[q].w, A[q].w, C[q].w);
    }
  } else {
    for (int e = e0; e < E; e++) ins(src[e], dst[e], amount[e], count[e]);
  }
}

// ========== merged: binB (blocks 0..nbkt-1) + pre_gemm (rest) ==========
__global__ __launch_bounds__(256) void binB_pre_k(const int2* __restrict__ payload,
                                                  const int* __restrict__ bbase,
                                                  int2* __restrict__ edge_s,
                                                  const float* __restrict__ h,
                                                  const float* __restrict__ fc_w,
                                                  const float* __restrict__ fc_b,
                                                  float* __restrict__ G1,
                                                  __half2* __restrict__ P,
                                                  int E, int nbkt, int N) {
  __shared__ float hs[NB * FDIM];   // 32 KB; binB reuses the first 3 KB as ints
  const int t = threadIdx.x;
  if ((int)blockIdx.x < nbkt) {
    // ---------------- binB: fine counting sort within bucket ----------------
    int* fcnt = (int*)hs;
    int* tmp  = fcnt + 256;
    int* fcur = tmp + 256;
    const int b = blockIdx.x;
    const int base = bbase[b];
    const int end  = bbase[b + 1];
    fcnt[t] = 0;
    __syncthreads();
    for (int i = base + t; i < end; i += 256)
      atomicAdd(&fcnt[(payload[i].x >> 20) & BMASK], 1);
    __syncthreads();
    int x = fcnt[t];
    tmp[t] = x; __syncthreads();
    for (int off = 1; off < 256; off <<= 1) {
      int v = (t >= off) ? tmp[t - off] : 0;
      __syncthreads();
      tmp[t] += v; __syncthreads();
    }
    fcur[t] = base + tmp[t] - x;
    __syncthreads();
    for (int i = base + t; i < end; i += 256) {
      int2 v = payload[i];
      int pos = atomicAdd(&fcur[(v.x >> 20) & BMASK], 1);
      edge_s[pos] = v;
    }
  } else {
    // ---------------- pre_gemm: G1 fp32; P = half2(G2, h) ----------------
    const int o = t & 63, half = (t >> 6) & 1, rg = t >> 7;
    float w[FDIM];
    const float* wrow = fc_w + o * 128 + half * 64;
    #pragma unroll
    for (int f = 0; f < FDIM; f += 4) {
      float4 v = *(const float4*)(wrow + f);
      w[f] = v.x; w[f + 1] = v.y; w[f + 2] = v.z; w[f + 3] = v.w;
    }
    const float bias = (half == 0) ? fc_b[o] : 0.0f;
    const int n0 = (blockIdx.x - nbkt) * NB;
    const int nrows = min(NB, N - n0);
    {
      const float4* hsrc = (const float4*)(h + (size_t)n0 * FDIM);
      float4* hd = (float4*)hs;
      for (int i = t; i < nrows * (FDIM / 4); i += 256) hd[i] = hsrc[i];
    }
    __syncthreads();
    const int r0 = rg * 64;
    const int r1 = min(r0 + 64, nrows);
    for (int n = r0; n < r1; n++) {
      float acc = bias;
      #pragma unroll
      for (int f = 0; f < FDIM; f += 4) {
        float4 hv = *(const float4*)(&hs[n * FDIM + f]);
        acc += hv.x * w[f] + hv.y * w[f + 1] + hv.z * w[f + 2] + hv.w * w[f + 3];
      }
      if (half == 0) {
        G1[(size_t)(n0 + n) * FDIM + o] = acc;
      } else {
        P[(size_t)(n0 + n) * FDIM + o] =
            __halves2half2(__float2half(acc), __float2half(hs[n * FDIM + o]));
      }
    }
  }
}

__device__ __forceinline__ float2 unpack_h2(unsigned u) {
  __half2 v = *(__half2*)&u;
  return make_float2(__low2float(v), __high2float(v));
}

// ---------- fused: segmented edge-centric pass over node-sorted edges ----------
__global__ __launch_bounds__(256) void fused_k(const int2* __restrict__ edge_s,
                                               const int* __restrict__ bbase,
                                               const float* __restrict__ G1,
                                               const unsigned* __restrict__ P,
                                               double* __restrict__ colsum,
                                               float* __restrict__ out,
                                               int E, int nbkt) {
  const int lane = threadIdx.x & 63;
  const int wv = __builtin_amdgcn_readfirstlane(threadIdx.x >> 6);
  const int wid = blockIdx.x * 4 + wv;
  const int nw = gridDim.x * 4;
  float csum = 0.0f;
  const int per = (((E + nw - 1) / nw) + 63) & ~63;
  const int e0 = wid * per;
  const int e1 = min(e0 + per, E);
  if (e0 < E) {
    int lo = 0, hi = nbkt - 1;
    while (lo < hi) {
      int mid = (lo + hi + 1) >> 1;
      if (bbase[mid] <= e0) lo = mid; else hi = mid - 1;
    }
    int bkt = lo;
    int nextb = bbase[bkt + 1];
    int curnode = -1;
    bool firstf = true;
    float acc = 0.0f, g1 = 0.0f;
    auto flush_to = [&](int node) {
      if (curnode >= 0) {
        float* dp = out + (size_t)curnode * FDIM + lane;
        if (firstf) { atomicAdd(dp, acc); firstf = false; }
        else *dp = acc;
      }
      curnode = node; acc = 0.0f;
      g1 = G1[(size_t)node * FDIM + lane];
    };
    for (int c0 = e0; c0 < e1; c0 += 64) {
      const int m = min(64, e1 - c0);
      int2 p = make_int2(0, 0);
      if (lane < m) p = edge_s[c0 + lane];
      if (m == 64) {
        #pragma unroll 1
        for (int j = 0; j < 64; j += 16) {
          int dd[16], nd[16]; float ee[16]; unsigned uu[16];
          #pragma unroll
          for (int k = 0; k < 16; k++) {
            int x = __builtin_amdgcn_readlane(p.x, j + k);
            ee[k] = __int_as_float(__builtin_amdgcn_readlane(p.y, j + k));
            dd[k] = x & DMASK;
            nd[k] = (x >> 20) & BMASK;
          }
          #pragma unroll
          for (int k = 0; k < 16; k++) uu[k] = P[(size_t)dd[k] * FDIM + lane];
          #pragma unroll
          for (int k = 0; k < 16; k++) {
            int i = c0 + j + k;
            while (i >= nextb) { bkt++; nextb = bbase[bkt + 1]; }
            int node = (bkt << BSHIFT) + nd[k];
            if (node != curnode) flush_to(node);
            float2 v = unpack_h2(uu[k]);
            float sc = g1 + v.x;
            sc = fmaxf(sc, 0.01f * sc);
            float x = exp2f(sc * ee[k]);
            csum += x;
            acc += x * v.y;
          }
        }
      } else {
        for (int j = 0; j < m; j += 16) {
          const int rem = m - j;
          int dd[16], nd[16]; float ee[16]; unsigned uu[16];
          #pragma unroll
          for (int k = 0; k < 16; k++) {
            int x = __builtin_amdgcn_readlane(p.x, j + k);
            ee[k] = __int_as_float(__builtin_amdgcn_readlane(p.y, j + k));
            dd[k] = x & DMASK;
            nd[k] = (x >> 20) & BMASK;
          }
          #pragma unroll
          for (int k = 0; k < 16; k++) uu[k] = P[(size_t)dd[k] * FDIM + lane];
          #pragma unroll
          for (int k = 0; k < 16; k++) {
            if (k < rem) {
              int i = c0 + j + k;
              while (i >= nextb) { bkt++; nextb = bbase[bkt + 1]; }
              int node = (bkt << BSHIFT) + nd[k];
              if (node != curnode) flush_to(node);
              float2 v = unpack_h2(uu[k]);
              float sc = g1 + v.x;
              sc = fmaxf(sc, 0.01f * sc);
              float x = exp2f(sc * ee[k]);
              csum += x;
              acc += x * v.y;
            }
          }
        }
      }
    }
    if (curnode >= 0) atomicAdd(out + (size_t)curnode * FDIM + lane, acc);
  }
  __shared__ float part[256];
  part[threadIdx.x] = csum;
  __syncthreads();
  if (threadIdx.x < 64) {
    float tot = part[threadIdx.x] + part[threadIdx.x + 64] +
                part[threadIdx.x + 128] + part[threadIdx.x + 192];
    atomicAdd(&colsum[threadIdx.x * 16], (double)tot);
  }
}

// ---------- epilogue: out *= 1/colsum[feature], float4 ----------
__global__ __launch_bounds__(256) void scale_k(float4* __restrict__ out4,
                                               const double* __restrict__ colsum,
                                               int total4) {
  __shared__ float rinv_s[64];
  if (threadIdx.x < 64) rinv_s[threadIdx.x] = (float)(1.0 / colsum[threadIdx.x * 16]);
  __syncthreads();
  const float4* r4 = (const float4*)rinv_s;
  int idx = blockIdx.x * blockDim.x + threadIdx.x;
  int stride = gridDim.x * blockDim.x;
  for (int i = idx; i < total4; i += stride) {
    float4 v = out4[i];
    float4 r = r4[i & 15];
    v.x *= r.x; v.y *= r.y; v.z *= r.z; v.w *= r.w;
    out4[i] = v;
  }
}

extern "C" void kernel_launch(void* const* d_in, const int* in_sizes, int n_in,
                              void* d_out, int out_size, void* d_ws, size_t ws_size,
                              hipStream_t stream) {
  const float* h      = (const float*)d_in[0];
  const int*   adj    = (const int*)d_in[1];
  const float* amount = (const float*)d_in[2];
  const float* count  = (const float*)d_in[3];
  const float* fc_w   = (const float*)d_in[4];
  const float* fc_b   = (const float*)d_in[5];
  float* out = (float*)d_out;

  const int E = in_sizes[2];
  const int N = in_sizes[0] / FDIM;
  const int* src = adj;
  const int* dst = adj + E;
  const int nbkt  = (N + BMASK) >> BSHIFT;           // 391
  const int nblkA = (E + CHUNKA - 1) / CHUNKA;       // 489 (co-resident: 2 blk/CU)

  // ---- workspace layout (256B-aligned) ----
  char* ws = (char*)d_ws;
  size_t off = 0;
  auto alloc = [&](size_t bytes) { void* p = ws + off; off += (bytes + 255) & ~(size_t)255; return p; };
  float*    G1       = (float*)alloc((size_t)N * FDIM * sizeof(float));
  __half2*  P        = (__half2*)alloc((size_t)N * FDIM * sizeof(__half2));
  int2*     edge_s   = (int2*)alloc((size_t)E * sizeof(int2));
  int2*     payload  = (int2*)alloc((size_t)E * sizeof(int2));
  int*      bktTotal = (int*)alloc(MAXBKT * sizeof(int));
  double*   colsum   = (double*)alloc(1024 * sizeof(double));
  int*      bbase    = (int*)alloc((MAXBKT + 1) * sizeof(int));
  int*      cursor   = (int*)alloc(MAXBKT * sizeof(int));
  float4*   mmpart   = (float4*)alloc((size_t)nblkA * sizeof(float4));
  float*    mmf      = (float*)alloc(4 * sizeof(float));

  // cooperative build: zero + count + scan + scatter in one launch
  {
    void* args[] = {(void*)&src, (void*)&dst, (void*)&amount, (void*)&count,
                    (void*)&out, (void*)&bktTotal, (void*)&colsum, (void*)&bbase,
                    (void*)&cursor, (void*)&mmpart, (void*)&mmf, (void*)&payload,
                    (void*)&E, (void*)&N, (void*)&nbkt, (void*)&nblkA};
    hipLaunchCooperativeKernel((void*)build_k, dim3(nblkA), dim3(256), args, 0, stream);
  }
  binB_pre_k<<<nbkt + (N + NB - 1) / NB, 256, 0, stream>>>(
      payload, bbase, edge_s, h, fc_w, fc_b, G1, P, E, nbkt, N);
  fused_k<<<4096, 256, 0, stream>>>(edge_s, bbase, G1, (const unsigned*)P, colsum, out, E, nbkt);
  scale_k<<<1024, 256, 0, stream>>>((float4*)out, colsum, N * FDIM / 4);
}